// Round 1
// baseline (443.211 us; speedup 1.0000x reference)
//
#include <hip/hip_runtime.h>
#include <hip/hip_bf16.h>

// GCNConv: out = relu( D^{-1/2} (A + I) D^{-1/2} (x @ W) + b )
// Pipeline:
//   1. init deg/cursor = 0
//   2. count in-degree per dst (int atomics)
//   3. exclusive scan over deg -> rowstart (3-kernel scan); fused dinv = rsqrt(deg+1)
//   4. fill CSR (edges bucketed by dst) via atomic cursors
//   5. xs = dinv[n] * (x[n] @ W)    (fp32 vector GEMM, 64-row tile, 8x4 reg tile)
//   6. out[n] = relu( dinv[n] * (xs[n] + sum_{s in in(n)} xs[s]) + b )

#define SCAN_BLK 256

__global__ __launch_bounds__(256) void k_init(int* __restrict__ deg,
                                              int* __restrict__ cursor, int N) {
    int i = blockIdx.x * 256 + threadIdx.x;
    if (i < N) { deg[i] = 0; cursor[i] = 0; }
}

__global__ __launch_bounds__(256) void k_count(const int* __restrict__ dst,
                                               int* __restrict__ deg, int E) {
    int e = blockIdx.x * 256 + threadIdx.x;
    if (e < E) atomicAdd(&deg[dst[e]], 1);
}

// per-block sums of deg
__global__ __launch_bounds__(SCAN_BLK) void k_scanA(const int* __restrict__ deg,
                                                    int* __restrict__ bsum, int N) {
    __shared__ int s[SCAN_BLK];
    int t = threadIdx.x;
    int i = blockIdx.x * SCAN_BLK + t;
    s[t] = (i < N) ? deg[i] : 0;
    __syncthreads();
    for (int off = SCAN_BLK / 2; off > 0; off >>= 1) {
        if (t < off) s[t] += s[t + off];
        __syncthreads();
    }
    if (t == 0) bsum[blockIdx.x] = s[0];
}

// single-block exclusive scan of block sums (nb <= 512)
__global__ __launch_bounds__(512) void k_scanB(int* __restrict__ bsum, int nb) {
    __shared__ int s[512];
    int t = threadIdx.x;
    int v = (t < nb) ? bsum[t] : 0;
    s[t] = v;
    __syncthreads();
    for (int off = 1; off < 512; off <<= 1) {
        int add = (t >= off) ? s[t - off] : 0;
        __syncthreads();
        s[t] += add;
        __syncthreads();
    }
    if (t < nb) bsum[t] = s[t] - v;   // exclusive
}

// per-block exclusive scan + block offset -> rowstart; fused dinv
__global__ __launch_bounds__(SCAN_BLK) void k_scanC(const int* __restrict__ deg,
                                                    const int* __restrict__ bsum,
                                                    int* __restrict__ rowstart,
                                                    float* __restrict__ dinv, int N) {
    __shared__ int s[SCAN_BLK];
    int t = threadIdx.x;
    int i = blockIdx.x * SCAN_BLK + t;
    int v = (i < N) ? deg[i] : 0;
    s[t] = v;
    __syncthreads();
    for (int off = 1; off < SCAN_BLK; off <<= 1) {
        int add = (t >= off) ? s[t - off] : 0;
        __syncthreads();
        s[t] += add;
        __syncthreads();
    }
    if (i < N) {
        rowstart[i] = s[t] - v + bsum[blockIdx.x];
        dinv[i] = rsqrtf((float)(v + 1));   // +1 self-loop
    }
}

__global__ __launch_bounds__(256) void k_fill(const int* __restrict__ src,
                                              const int* __restrict__ dst,
                                              const int* __restrict__ rowstart,
                                              int* __restrict__ cursor,
                                              int* __restrict__ csr_src, int E) {
    int e = blockIdx.x * 256 + threadIdx.x;
    if (e < E) {
        int d = dst[e];
        int p = atomicAdd(&cursor[d], 1);
        csr_src[rowstart[d] + p] = src[e];
    }
}

// xs[row] = dinv[row] * (x[row] @ W).  Tile: 64 rows x 128 cols per block,
// 256 threads, each thread 8 rows x 4 cols.
__global__ __launch_bounds__(256) void k_gemm(const float* __restrict__ x,
                                              const float* __restrict__ W,
                                              const float* __restrict__ dinv,
                                              float* __restrict__ xs_out, int N) {
    __shared__ float xs[64][128];
    const int row0 = blockIdx.x * 64;
    const int t = threadIdx.x;
    const int rows = min(64, N - row0);

    // stage x tile (contiguous 32 KB) into LDS
    const float4* xg = (const float4*)(x + (size_t)row0 * 128);
    for (int i = t; i < 64 * 32; i += 256) {
        float4 v;
        if (i < rows * 32) v = xg[i];
        else               v = make_float4(0.f, 0.f, 0.f, 0.f);
        ((float4*)&xs[0][0])[i] = v;
    }
    __syncthreads();

    const int tx = t & 31;   // col group: cols tx*4 .. +3
    const int ty = t >> 5;   // row group: rows ty*8 .. +7

    float acc[8][4];
#pragma unroll
    for (int r = 0; r < 8; ++r)
#pragma unroll
        for (int c = 0; c < 4; ++c) acc[r][c] = 0.f;

    const float4* Wv = (const float4*)W;   // W[k][h], row-major
#pragma unroll 4
    for (int k = 0; k < 128; k += 4) {
        float4 w0 = Wv[(k + 0) * 32 + tx];
        float4 w1 = Wv[(k + 1) * 32 + tx];
        float4 w2 = Wv[(k + 2) * 32 + tx];
        float4 w3 = Wv[(k + 3) * 32 + tx];
#pragma unroll
        for (int r = 0; r < 8; ++r) {
            float4 xv = *(const float4*)&xs[ty * 8 + r][k];
            acc[r][0] += xv.x * w0.x + xv.y * w1.x + xv.z * w2.x + xv.w * w3.x;
            acc[r][1] += xv.x * w0.y + xv.y * w1.y + xv.z * w2.y + xv.w * w3.y;
            acc[r][2] += xv.x * w0.z + xv.y * w1.z + xv.z * w2.z + xv.w * w3.z;
            acc[r][3] += xv.x * w0.w + xv.y * w1.w + xv.z * w2.w + xv.w * w3.w;
        }
    }

#pragma unroll
    for (int r = 0; r < 8; ++r) {
        int row = row0 + ty * 8 + r;
        if (row < N) {
            float dv = dinv[row];
            float4 o = make_float4(acc[r][0] * dv, acc[r][1] * dv,
                                   acc[r][2] * dv, acc[r][3] * dv);
            ((float4*)(xs_out + (size_t)row * 128))[tx] = o;
        }
    }
}

// one wave per node; lane holds float2 of the 128-wide feature
__global__ __launch_bounds__(256) void k_aggregate(const float* __restrict__ xs,
                                                   const int* __restrict__ csr_src,
                                                   const int* __restrict__ rowstart,
                                                   const int* __restrict__ deg,
                                                   const float* __restrict__ dinv,
                                                   const float* __restrict__ bias,
                                                   float* __restrict__ out, int N) {
    const int wave = threadIdx.x >> 6;
    const int lane = threadIdx.x & 63;
    const int n = blockIdx.x * 4 + wave;
    if (n >= N) return;

    const int rs = rowstart[n];
    const int c = deg[n];
    const float dv = dinv[n];

    float2 acc = ((const float2*)(xs + (size_t)n * 128))[lane];  // self-loop term

    int i = 0;
    for (; i + 1 < c; i += 2) {
        int s0 = csr_src[rs + i];
        int s1 = csr_src[rs + i + 1];
        float2 v0 = ((const float2*)(xs + (size_t)s0 * 128))[lane];
        float2 v1 = ((const float2*)(xs + (size_t)s1 * 128))[lane];
        acc.x += v0.x + v1.x;
        acc.y += v0.y + v1.y;
    }
    if (i < c) {
        int s0 = csr_src[rs + i];
        float2 v0 = ((const float2*)(xs + (size_t)s0 * 128))[lane];
        acc.x += v0.x;
        acc.y += v0.y;
    }

    float2 bb = ((const float2*)bias)[lane];
    float ox = fmaxf(dv * acc.x + bb.x, 0.f);
    float oy = fmaxf(dv * acc.y + bb.y, 0.f);
    ((float2*)(out + (size_t)n * 128))[lane] = make_float2(ox, oy);
}

extern "C" void kernel_launch(void* const* d_in, const int* in_sizes, int n_in,
                              void* d_out, int out_size, void* d_ws, size_t ws_size,
                              hipStream_t stream) {
    const float* x   = (const float*)d_in[0];
    const int*   ei  = (const int*)d_in[1];     // [2, E] flat: src then dst
    const float* W   = (const float*)d_in[2];
    const float* b   = (const float*)d_in[3];
    float*       out = (float*)d_out;

    const int N = in_sizes[0] / 128;
    const int E = in_sizes[1] / 2;
    const int* src = ei;
    const int* dst = ei + E;

    // workspace carve (256B aligned)
    auto align = [](size_t v) { return (v + 255) & ~(size_t)255; };
    char* p = (char*)d_ws;
    int*   deg      = (int*)p;   p += align((size_t)N * 4);
    int*   cursor   = (int*)p;   p += align((size_t)N * 4);
    int*   rowstart = (int*)p;   p += align((size_t)N * 4);
    int*   bsum     = (int*)p;   p += align(512 * 4);
    float* dinv     = (float*)p; p += align((size_t)N * 4);
    int*   csr_src  = (int*)p;   p += align((size_t)E * 4);
    float* xs       = (float*)p; p += align((size_t)N * 128 * 4);
    (void)ws_size;

    const int nbN = (N + 255) / 256;   // 391 for N=100000 (<=512 required by scanB)
    const int nbE = (E + 255) / 256;

    k_init<<<nbN, 256, 0, stream>>>(deg, cursor, N);
    k_count<<<nbE, 256, 0, stream>>>(dst, deg, E);
    k_scanA<<<nbN, 256, 0, stream>>>(deg, bsum, N);
    k_scanB<<<1, 512, 0, stream>>>(bsum, nbN);
    k_scanC<<<nbN, 256, 0, stream>>>(deg, bsum, rowstart, dinv, N);
    k_fill<<<nbE, 256, 0, stream>>>(src, dst, rowstart, cursor, csr_src, E);
    k_gemm<<<(N + 63) / 64, 256, 0, stream>>>(x, W, dinv, xs, N);
    k_aggregate<<<(N + 3) / 4, 256, 0, stream>>>(xs, csr_src, rowstart, deg, dinv, b,
                                                 out, N);
}

// Round 2
// 414.304 us; speedup vs baseline: 1.0698x; 1.0698x over previous
//
#include <hip/hip_runtime.h>
#include <hip/hip_bf16.h>

// GCNConv: out = relu( D^{-1/2} (A + I) D^{-1/2} (x @ W) + b )
// Pipeline:
//   1. init deg = 0
//   2. count in-degree per dst (int atomics)
//   3. exclusive scan deg -> rowstart (+cursor seed) ; dinv = rsqrt(deg+1)
//   4. fill CSR (edges bucketed by dst) via atomic cursors (1 atomic + 1 store)
//   5. xs = bf16( dinv[n] * (x[n] @ W) )   (fp32 vector GEMM, bf16-packed out)
//   6. out[n] = relu( dinv[n] * (xs[n] + sum_{s in in(n)} xs[s]) + b )  (fp32 out)

#define SCAN_BLK 256

__device__ inline float2 b2f2(unsigned u) {
    float2 r;
    r.x = __uint_as_float(u << 16);
    r.y = __uint_as_float(u & 0xffff0000u);
    return r;
}

__device__ inline unsigned f2b2(float x, float y) {
    __hip_bfloat16 bx = __float2bfloat16(x);   // RNE
    __hip_bfloat16 by = __float2bfloat16(y);
    unsigned short ux = *(unsigned short*)&bx;
    unsigned short uy = *(unsigned short*)&by;
    return (unsigned)ux | ((unsigned)uy << 16);
}

__global__ __launch_bounds__(256) void k_init(int* __restrict__ deg, int N) {
    int i = blockIdx.x * 256 + threadIdx.x;
    if (i < N) deg[i] = 0;
}

__global__ __launch_bounds__(256) void k_count(const int* __restrict__ dst,
                                               int* __restrict__ deg, int E) {
    int e = blockIdx.x * 256 + threadIdx.x;
    if (e < E) atomicAdd(&deg[dst[e]], 1);
}

// per-block sums of deg
__global__ __launch_bounds__(SCAN_BLK) void k_scanA(const int* __restrict__ deg,
                                                    int* __restrict__ bsum, int N) {
    __shared__ int s[SCAN_BLK];
    int t = threadIdx.x;
    int i = blockIdx.x * SCAN_BLK + t;
    s[t] = (i < N) ? deg[i] : 0;
    __syncthreads();
    for (int off = SCAN_BLK / 2; off > 0; off >>= 1) {
        if (t < off) s[t] += s[t + off];
        __syncthreads();
    }
    if (t == 0) bsum[blockIdx.x] = s[0];
}

// single-block exclusive scan of block sums (nb <= 512)
__global__ __launch_bounds__(512) void k_scanB(int* __restrict__ bsum, int nb) {
    __shared__ int s[512];
    int t = threadIdx.x;
    int v = (t < nb) ? bsum[t] : 0;
    s[t] = v;
    __syncthreads();
    for (int off = 1; off < 512; off <<= 1) {
        int add = (t >= off) ? s[t - off] : 0;
        __syncthreads();
        s[t] += add;
        __syncthreads();
    }
    if (t < nb) bsum[t] = s[t] - v;   // exclusive
}

// per-block exclusive scan + block offset -> rowstart & cursor seed; fused dinv
__global__ __launch_bounds__(SCAN_BLK) void k_scanC(const int* __restrict__ deg,
                                                    const int* __restrict__ bsum,
                                                    int* __restrict__ rowstart,
                                                    int* __restrict__ cursor,
                                                    float* __restrict__ dinv, int N) {
    __shared__ int s[SCAN_BLK];
    int t = threadIdx.x;
    int i = blockIdx.x * SCAN_BLK + t;
    int v = (i < N) ? deg[i] : 0;
    s[t] = v;
    __syncthreads();
    for (int off = 1; off < SCAN_BLK; off <<= 1) {
        int add = (t >= off) ? s[t - off] : 0;
        __syncthreads();
        s[t] += add;
        __syncthreads();
    }
    if (i < N) {
        int rs = s[t] - v + bsum[blockIdx.x];
        rowstart[i] = rs;
        cursor[i]   = rs;
        dinv[i] = rsqrtf((float)(v + 1));   // +1 self-loop
    }
}

__global__ __launch_bounds__(256) void k_fill(const int* __restrict__ src,
                                              const int* __restrict__ dst,
                                              int* __restrict__ cursor,
                                              int* __restrict__ csr_src, int E) {
    int e = blockIdx.x * 256 + threadIdx.x;
    if (e < E) {
        int p = atomicAdd(&cursor[dst[e]], 1);
        csr_src[p] = src[e];
    }
}

// xs[row] = bf16(dinv[row] * (x[row] @ W)).  Tile: 64 rows x 128 cols per block,
// 256 threads, each thread 8 rows x 4 cols.  xs packed as bf16x2 (unsigned).
__global__ __launch_bounds__(256) void k_gemm(const float* __restrict__ x,
                                              const float* __restrict__ W,
                                              const float* __restrict__ dinv,
                                              unsigned* __restrict__ xs_out, int N) {
    __shared__ float xs[64][128];
    const int row0 = blockIdx.x * 64;
    const int t = threadIdx.x;
    const int rows = min(64, N - row0);

    // stage x tile (contiguous 32 KB) into LDS
    const float4* xg = (const float4*)(x + (size_t)row0 * 128);
    for (int i = t; i < 64 * 32; i += 256) {
        float4 v;
        if (i < rows * 32) v = xg[i];
        else               v = make_float4(0.f, 0.f, 0.f, 0.f);
        ((float4*)&xs[0][0])[i] = v;
    }
    __syncthreads();

    const int tx = t & 31;   // col group: cols tx*4 .. +3
    const int ty = t >> 5;   // row group: rows ty*8 .. +7

    float acc[8][4];
#pragma unroll
    for (int r = 0; r < 8; ++r)
#pragma unroll
        for (int c = 0; c < 4; ++c) acc[r][c] = 0.f;

    const float4* Wv = (const float4*)W;   // W[k][h], row-major
#pragma unroll 4
    for (int k = 0; k < 128; k += 4) {
        float4 w0 = Wv[(k + 0) * 32 + tx];
        float4 w1 = Wv[(k + 1) * 32 + tx];
        float4 w2 = Wv[(k + 2) * 32 + tx];
        float4 w3 = Wv[(k + 3) * 32 + tx];
#pragma unroll
        for (int r = 0; r < 8; ++r) {
            float4 xv = *(const float4*)&xs[ty * 8 + r][k];
            acc[r][0] += xv.x * w0.x + xv.y * w1.x + xv.z * w2.x + xv.w * w3.x;
            acc[r][1] += xv.x * w0.y + xv.y * w1.y + xv.z * w2.y + xv.w * w3.y;
            acc[r][2] += xv.x * w0.z + xv.y * w1.z + xv.z * w2.z + xv.w * w3.z;
            acc[r][3] += xv.x * w0.w + xv.y * w1.w + xv.z * w2.w + xv.w * w3.w;
        }
    }

#pragma unroll
    for (int r = 0; r < 8; ++r) {
        int row = row0 + ty * 8 + r;
        if (row < N) {
            float dv = dinv[row];
            uint2 o;
            o.x = f2b2(acc[r][0] * dv, acc[r][1] * dv);
            o.y = f2b2(acc[r][2] * dv, acc[r][3] * dv);
            ((uint2*)(xs_out + (size_t)row * 64))[tx] = o;
        }
    }
}

// one wave per node; lane holds bf16x2 of the 128-wide feature
__global__ __launch_bounds__(256) void k_aggregate(const unsigned* __restrict__ xs,
                                                   const int* __restrict__ csr_src,
                                                   const int* __restrict__ rowstart,
                                                   const int* __restrict__ deg,
                                                   const float* __restrict__ dinv,
                                                   const float* __restrict__ bias,
                                                   float* __restrict__ out, int N) {
    const int wave = threadIdx.x >> 6;
    const int lane = threadIdx.x & 63;
    const int n = blockIdx.x * 4 + wave;
    if (n >= N) return;

    const int rs = rowstart[n];
    const int c = deg[n];
    const float dv = dinv[n];

    float2 acc = b2f2(xs[(size_t)n * 64 + lane]);  // self-loop term

    int i = 0;
    for (; i + 4 <= c; i += 4) {
        int s0 = csr_src[rs + i];
        int s1 = csr_src[rs + i + 1];
        int s2 = csr_src[rs + i + 2];
        int s3 = csr_src[rs + i + 3];
        unsigned u0 = xs[(size_t)s0 * 64 + lane];
        unsigned u1 = xs[(size_t)s1 * 64 + lane];
        unsigned u2 = xs[(size_t)s2 * 64 + lane];
        unsigned u3 = xs[(size_t)s3 * 64 + lane];
        float2 v0 = b2f2(u0), v1 = b2f2(u1), v2 = b2f2(u2), v3 = b2f2(u3);
        acc.x += (v0.x + v1.x) + (v2.x + v3.x);
        acc.y += (v0.y + v1.y) + (v2.y + v3.y);
    }
    for (; i < c; ++i) {
        int s0 = csr_src[rs + i];
        float2 v0 = b2f2(xs[(size_t)s0 * 64 + lane]);
        acc.x += v0.x;
        acc.y += v0.y;
    }

    float2 bb = ((const float2*)bias)[lane];
    float ox = fmaxf(dv * acc.x + bb.x, 0.f);
    float oy = fmaxf(dv * acc.y + bb.y, 0.f);
    ((float2*)(out + (size_t)n * 128))[lane] = make_float2(ox, oy);
}

extern "C" void kernel_launch(void* const* d_in, const int* in_sizes, int n_in,
                              void* d_out, int out_size, void* d_ws, size_t ws_size,
                              hipStream_t stream) {
    const float* x   = (const float*)d_in[0];
    const int*   ei  = (const int*)d_in[1];     // [2, E] flat: src then dst
    const float* W   = (const float*)d_in[2];
    const float* b   = (const float*)d_in[3];
    float*       out = (float*)d_out;

    const int N = in_sizes[0] / 128;
    const int E = in_sizes[1] / 2;
    const int* src = ei;
    const int* dst = ei + E;

    // workspace carve (256B aligned)
    auto align = [](size_t v) { return (v + 255) & ~(size_t)255; };
    char* p = (char*)d_ws;
    int*      deg      = (int*)p;      p += align((size_t)N * 4);
    int*      cursor   = (int*)p;      p += align((size_t)N * 4);
    int*      rowstart = (int*)p;      p += align((size_t)N * 4);
    int*      bsum     = (int*)p;      p += align(512 * 4);
    float*    dinv     = (float*)p;    p += align((size_t)N * 4);
    int*      csr_src  = (int*)p;      p += align((size_t)E * 4);
    unsigned* xs       = (unsigned*)p; p += align((size_t)N * 64 * 4);  // bf16x2
    (void)ws_size;

    const int nbN = (N + 255) / 256;   // 391 for N=100000 (<=512 required by scanB)
    const int nbE = (E + 255) / 256;

    k_init<<<nbN, 256, 0, stream>>>(deg, N);
    k_count<<<nbE, 256, 0, stream>>>(dst, deg, E);
    k_scanA<<<nbN, 256, 0, stream>>>(deg, bsum, N);
    k_scanB<<<1, 512, 0, stream>>>(bsum, nbN);
    k_scanC<<<nbN, 256, 0, stream>>>(deg, bsum, rowstart, cursor, dinv, N);
    k_fill<<<nbE, 256, 0, stream>>>(src, dst, cursor, csr_src, E);
    k_gemm<<<(N + 63) / 64, 256, 0, stream>>>(x, W, dinv, xs, N);
    k_aggregate<<<(N + 3) / 4, 256, 0, stream>>>(xs, csr_src, rowstart, deg, dinv, b,
                                                 out, N);
}

// Round 3
// 354.513 us; speedup vs baseline: 1.2502x; 1.1687x over previous
//
#include <hip/hip_runtime.h>
#include <hip/hip_bf16.h>

// GCNConv: out = relu( D^{-1/2} (A + I) D^{-1/2} (x @ W) + b )
// Pipeline:
//   1. init deg = 0
//   2. count in-degree per dst (int atomics), capturing per-edge rank
//   3. exclusive scan deg -> rowstart ; dinv = rsqrt(deg+1)
//   4. fill CSR: pos = rowstart[dst] + rank  (NO atomics, nt scatter store)
//   5. xs = bf16( dinv[n] * (x[n] @ W) )   (fp32 vector GEMM, bf16-packed out)
//   6. out[n] = relu( dinv[n] * (xs[n] + sum_{s in in(n)} xs[s]) + b )

#define SCAN_BLK 256

__device__ inline float2 b2f2(unsigned u) {
    float2 r;
    r.x = __uint_as_float(u << 16);
    r.y = __uint_as_float(u & 0xffff0000u);
    return r;
}

__device__ inline unsigned f2b2(float x, float y) {
    __hip_bfloat16 bx = __float2bfloat16(x);   // RNE
    __hip_bfloat16 by = __float2bfloat16(y);
    unsigned short ux = *(unsigned short*)&bx;
    unsigned short uy = *(unsigned short*)&by;
    return (unsigned)ux | ((unsigned)uy << 16);
}

__global__ __launch_bounds__(256) void k_init(int* __restrict__ deg, int N) {
    int i = blockIdx.x * 256 + threadIdx.x;
    if (i < N) deg[i] = 0;
}

// 4 edges per thread, independent atomics; capture rank for the fill pass.
__global__ __launch_bounds__(256) void k_count(const int* __restrict__ dst,
                                               int* __restrict__ deg,
                                               int* __restrict__ rank, int E) {
    int base = blockIdx.x * 1024 + threadIdx.x;
#pragma unroll
    for (int j = 0; j < 4; ++j) {
        int e = base + j * 256;
        if (e < E) rank[e] = atomicAdd(&deg[dst[e]], 1);
    }
}

// per-block sums of deg
__global__ __launch_bounds__(SCAN_BLK) void k_scanA(const int* __restrict__ deg,
                                                    int* __restrict__ bsum, int N) {
    __shared__ int s[SCAN_BLK];
    int t = threadIdx.x;
    int i = blockIdx.x * SCAN_BLK + t;
    s[t] = (i < N) ? deg[i] : 0;
    __syncthreads();
    for (int off = SCAN_BLK / 2; off > 0; off >>= 1) {
        if (t < off) s[t] += s[t + off];
        __syncthreads();
    }
    if (t == 0) bsum[blockIdx.x] = s[0];
}

// single-block exclusive scan of block sums (nb <= 512)
__global__ __launch_bounds__(512) void k_scanB(int* __restrict__ bsum, int nb) {
    __shared__ int s[512];
    int t = threadIdx.x;
    int v = (t < nb) ? bsum[t] : 0;
    s[t] = v;
    __syncthreads();
    for (int off = 1; off < 512; off <<= 1) {
        int add = (t >= off) ? s[t - off] : 0;
        __syncthreads();
        s[t] += add;
        __syncthreads();
    }
    if (t < nb) bsum[t] = s[t] - v;   // exclusive
}

// per-block exclusive scan + block offset -> rowstart; fused dinv
__global__ __launch_bounds__(SCAN_BLK) void k_scanC(const int* __restrict__ deg,
                                                    const int* __restrict__ bsum,
                                                    int* __restrict__ rowstart,
                                                    float* __restrict__ dinv, int N) {
    __shared__ int s[SCAN_BLK];
    int t = threadIdx.x;
    int i = blockIdx.x * SCAN_BLK + t;
    int v = (i < N) ? deg[i] : 0;
    s[t] = v;
    __syncthreads();
    for (int off = 1; off < SCAN_BLK; off <<= 1) {
        int add = (t >= off) ? s[t - off] : 0;
        __syncthreads();
        s[t] += add;
        __syncthreads();
    }
    if (i < N) {
        rowstart[i] = s[t] - v + bsum[blockIdx.x];
        dinv[i] = rsqrtf((float)(v + 1));   // +1 self-loop
    }
}

// Atomic-free fill: position is rowstart[dst] + captured rank.
// 4 edges per thread for MLP; nontemporal scatter store.
__global__ __launch_bounds__(256) void k_fill(const int* __restrict__ src,
                                              const int* __restrict__ dst,
                                              const int* __restrict__ rowstart,
                                              const int* __restrict__ rank,
                                              int* __restrict__ csr_src, int E) {
    int base = blockIdx.x * 1024 + threadIdx.x;
#pragma unroll
    for (int j = 0; j < 4; ++j) {
        int e = base + j * 256;
        if (e < E) {
            int pos = rowstart[dst[e]] + rank[e];
            __builtin_nontemporal_store(src[e], &csr_src[pos]);
        }
    }
}

// xs[row] = bf16(dinv[row] * (x[row] @ W)).  Tile: 64 rows x 128 cols per block,
// 256 threads, each thread 8 rows x 4 cols.  xs packed as bf16x2 (unsigned).
__global__ __launch_bounds__(256) void k_gemm(const float* __restrict__ x,
                                              const float* __restrict__ W,
                                              const float* __restrict__ dinv,
                                              unsigned* __restrict__ xs_out, int N) {
    __shared__ float xs[64][128];
    const int row0 = blockIdx.x * 64;
    const int t = threadIdx.x;
    const int rows = min(64, N - row0);

    // stage x tile (contiguous 32 KB) into LDS
    const float4* xg = (const float4*)(x + (size_t)row0 * 128);
    for (int i = t; i < 64 * 32; i += 256) {
        float4 v;
        if (i < rows * 32) v = xg[i];
        else               v = make_float4(0.f, 0.f, 0.f, 0.f);
        ((float4*)&xs[0][0])[i] = v;
    }
    __syncthreads();

    const int tx = t & 31;   // col group: cols tx*4 .. +3
    const int ty = t >> 5;   // row group: rows ty*8 .. +7

    float acc[8][4];
#pragma unroll
    for (int r = 0; r < 8; ++r)
#pragma unroll
        for (int c = 0; c < 4; ++c) acc[r][c] = 0.f;

    const float4* Wv = (const float4*)W;   // W[k][h], row-major
#pragma unroll 4
    for (int k = 0; k < 128; k += 4) {
        float4 w0 = Wv[(k + 0) * 32 + tx];
        float4 w1 = Wv[(k + 1) * 32 + tx];
        float4 w2 = Wv[(k + 2) * 32 + tx];
        float4 w3 = Wv[(k + 3) * 32 + tx];
#pragma unroll
        for (int r = 0; r < 8; ++r) {
            float4 xv = *(const float4*)&xs[ty * 8 + r][k];
            acc[r][0] += xv.x * w0.x + xv.y * w1.x + xv.z * w2.x + xv.w * w3.x;
            acc[r][1] += xv.x * w0.y + xv.y * w1.y + xv.z * w2.y + xv.w * w3.y;
            acc[r][2] += xv.x * w0.z + xv.y * w1.z + xv.z * w2.z + xv.w * w3.z;
            acc[r][3] += xv.x * w0.w + xv.y * w1.w + xv.z * w2.w + xv.w * w3.w;
        }
    }

#pragma unroll
    for (int r = 0; r < 8; ++r) {
        int row = row0 + ty * 8 + r;
        if (row < N) {
            float dv = dinv[row];
            uint2 o;
            o.x = f2b2(acc[r][0] * dv, acc[r][1] * dv);
            o.y = f2b2(acc[r][2] * dv, acc[r][3] * dv);
            ((uint2*)(xs_out + (size_t)row * 64))[tx] = o;
        }
    }
}

// one wave per node; lane holds bf16x2 of the 128-wide feature
__global__ __launch_bounds__(256) void k_aggregate(const unsigned* __restrict__ xs,
                                                   const int* __restrict__ csr_src,
                                                   const int* __restrict__ rowstart,
                                                   const int* __restrict__ deg,
                                                   const float* __restrict__ dinv,
                                                   const float* __restrict__ bias,
                                                   float* __restrict__ out, int N) {
    const int wave = threadIdx.x >> 6;
    const int lane = threadIdx.x & 63;
    const int n = blockIdx.x * 4 + wave;
    if (n >= N) return;

    const int rs = rowstart[n];
    const int c = deg[n];
    const float dv = dinv[n];

    float2 acc = b2f2(xs[(size_t)n * 64 + lane]);  // self-loop term

    int i = 0;
    for (; i + 8 <= c; i += 8) {
        int s[8];
#pragma unroll
        for (int j = 0; j < 8; ++j) s[j] = csr_src[rs + i + j];
        unsigned u[8];
#pragma unroll
        for (int j = 0; j < 8; ++j) u[j] = xs[(size_t)s[j] * 64 + lane];
#pragma unroll
        for (int j = 0; j < 8; ++j) {
            float2 v = b2f2(u[j]);
            acc.x += v.x;
            acc.y += v.y;
        }
    }
    for (; i < c; ++i) {
        int s0 = csr_src[rs + i];
        float2 v0 = b2f2(xs[(size_t)s0 * 64 + lane]);
        acc.x += v0.x;
        acc.y += v0.y;
    }

    float2 bb = ((const float2*)bias)[lane];
    float ox = fmaxf(dv * acc.x + bb.x, 0.f);
    float oy = fmaxf(dv * acc.y + bb.y, 0.f);
    ((float2*)(out + (size_t)n * 128))[lane] = make_float2(ox, oy);
}

extern "C" void kernel_launch(void* const* d_in, const int* in_sizes, int n_in,
                              void* d_out, int out_size, void* d_ws, size_t ws_size,
                              hipStream_t stream) {
    const float* x   = (const float*)d_in[0];
    const int*   ei  = (const int*)d_in[1];     // [2, E] flat: src then dst
    const float* W   = (const float*)d_in[2];
    const float* b   = (const float*)d_in[3];
    float*       out = (float*)d_out;

    const int N = in_sizes[0] / 128;
    const int E = in_sizes[1] / 2;
    const int* src = ei;
    const int* dst = ei + E;

    // workspace carve (256B aligned)
    auto align = [](size_t v) { return (v + 255) & ~(size_t)255; };
    char* p = (char*)d_ws;
    int*      deg      = (int*)p;      p += align((size_t)N * 4);
    int*      rowstart = (int*)p;      p += align((size_t)N * 4);
    int*      bsum     = (int*)p;      p += align(512 * 4);
    float*    dinv     = (float*)p;    p += align((size_t)N * 4);
    int*      rank     = (int*)p;      p += align((size_t)E * 4);
    int*      csr_src  = (int*)p;      p += align((size_t)E * 4);
    unsigned* xs       = (unsigned*)p; p += align((size_t)N * 64 * 4);  // bf16x2
    (void)ws_size;

    const int nbN  = (N + 255) / 256;   // 391 (<=512 required by scanB)
    const int nbE4 = (E + 1023) / 1024;

    k_init<<<nbN, 256, 0, stream>>>(deg, N);
    k_count<<<nbE4, 256, 0, stream>>>(dst, deg, rank, E);
    k_scanA<<<nbN, 256, 0, stream>>>(deg, bsum, N);
    k_scanB<<<1, 512, 0, stream>>>(bsum, nbN);
    k_scanC<<<nbN, 256, 0, stream>>>(deg, bsum, rowstart, dinv, N);
    k_fill<<<nbE4, 256, 0, stream>>>(src, dst, rowstart, rank, csr_src, E);
    k_gemm<<<(N + 63) / 64, 256, 0, stream>>>(x, W, dinv, xs, N);
    k_aggregate<<<(N + 3) / 4, 256, 0, stream>>>(xs, csr_src, rowstart, deg, dinv, b,
                                                 out, N);
}

// Round 4
// 318.944 us; speedup vs baseline: 1.3896x; 1.1115x over previous
//
#include <hip/hip_runtime.h>
#include <hip/hip_bf16.h>

// GCNConv: out = relu( D^{-1/2} (A + I) D^{-1/2} (x @ W) + b )
// Pipeline:
//   1. init deg = 0
//   2. count in-degree per dst (int atomics), capturing per-edge rank
//   3. exclusive scan deg -> rowstart ; dinv = rsqrt(deg+1)
//   4. fill CSR: pos = rowstart[dst] + rank  (NO atomics, nt scatter store)
//   5. Wt = bf16(W^T)  (once)
//   6. xs = bf16( dinv[n] * (x[n] @ W) )   via MFMA 16x16x32 bf16
//   7. out[n] = relu( dinv[n] * (xs[n] + sum_{s in in(n)} xs[s]) + b )
//      aggregate: reg-cached indices + 2-rows-per-gather (8B/lane)

#define SCAN_BLK 256

typedef short  short8 __attribute__((ext_vector_type(8)));
typedef float  f32x4  __attribute__((ext_vector_type(4)));

__device__ inline unsigned short f2b(float f) {   // fp32 -> bf16 RNE
    unsigned u = __float_as_uint(f);
    return (unsigned short)((u + 0x7fffu + ((u >> 16) & 1u)) >> 16);
}

__device__ inline unsigned f2b2(float x, float y) {
    return (unsigned)f2b(x) | ((unsigned)f2b(y) << 16);
}

__device__ inline void acc4(float4& a, uint2 u) {
    a.x += __uint_as_float(u.x << 16);
    a.y += __uint_as_float(u.x & 0xffff0000u);
    a.z += __uint_as_float(u.y << 16);
    a.w += __uint_as_float(u.y & 0xffff0000u);
}

__global__ __launch_bounds__(256) void k_init(int* __restrict__ deg, int N) {
    int i = blockIdx.x * 256 + threadIdx.x;
    if (i < N) deg[i] = 0;
}

// 4 edges per thread, independent atomics; capture rank for the fill pass.
__global__ __launch_bounds__(256) void k_count(const int* __restrict__ dst,
                                               int* __restrict__ deg,
                                               int* __restrict__ rank, int E) {
    int base = blockIdx.x * 1024 + threadIdx.x;
#pragma unroll
    for (int j = 0; j < 4; ++j) {
        int e = base + j * 256;
        if (e < E) rank[e] = atomicAdd(&deg[dst[e]], 1);
    }
}

__global__ __launch_bounds__(SCAN_BLK) void k_scanA(const int* __restrict__ deg,
                                                    int* __restrict__ bsum, int N) {
    __shared__ int s[SCAN_BLK];
    int t = threadIdx.x;
    int i = blockIdx.x * SCAN_BLK + t;
    s[t] = (i < N) ? deg[i] : 0;
    __syncthreads();
    for (int off = SCAN_BLK / 2; off > 0; off >>= 1) {
        if (t < off) s[t] += s[t + off];
        __syncthreads();
    }
    if (t == 0) bsum[blockIdx.x] = s[0];
}

__global__ __launch_bounds__(512) void k_scanB(int* __restrict__ bsum, int nb) {
    __shared__ int s[512];
    int t = threadIdx.x;
    int v = (t < nb) ? bsum[t] : 0;
    s[t] = v;
    __syncthreads();
    for (int off = 1; off < 512; off <<= 1) {
        int add = (t >= off) ? s[t - off] : 0;
        __syncthreads();
        s[t] += add;
        __syncthreads();
    }
    if (t < nb) bsum[t] = s[t] - v;   // exclusive
}

__global__ __launch_bounds__(SCAN_BLK) void k_scanC(const int* __restrict__ deg,
                                                    const int* __restrict__ bsum,
                                                    int* __restrict__ rowstart,
                                                    float* __restrict__ dinv, int N) {
    __shared__ int s[SCAN_BLK];
    int t = threadIdx.x;
    int i = blockIdx.x * SCAN_BLK + t;
    int v = (i < N) ? deg[i] : 0;
    s[t] = v;
    __syncthreads();
    for (int off = 1; off < SCAN_BLK; off <<= 1) {
        int add = (t >= off) ? s[t - off] : 0;
        __syncthreads();
        s[t] += add;
        __syncthreads();
    }
    if (i < N) {
        rowstart[i] = s[t] - v + bsum[blockIdx.x];
        dinv[i] = rsqrtf((float)(v + 1));   // +1 self-loop
    }
}

__global__ __launch_bounds__(256) void k_fill(const int* __restrict__ src,
                                              const int* __restrict__ dst,
                                              const int* __restrict__ rowstart,
                                              const int* __restrict__ rank,
                                              int* __restrict__ csr_src, int E) {
    int base = blockIdx.x * 1024 + threadIdx.x;
#pragma unroll
    for (int j = 0; j < 4; ++j) {
        int e = base + j * 256;
        if (e < E) {
            int pos = rowstart[dst[e]] + rank[e];
            __builtin_nontemporal_store(src[e], &csr_src[pos]);
        }
    }
}

// Wt[n][k] = bf16(W[k][n])  (128x128)
__global__ __launch_bounds__(256) void k_wconv(const float* __restrict__ W,
                                               unsigned short* __restrict__ Wt) {
    int i = blockIdx.x * 256 + threadIdx.x;   // 0..16383
    int k = i >> 7, n = i & 127;
    Wt[n * 128 + k] = f2b(W[k * 128 + n]);
}

// MFMA gemm: xs[row] = bf16(dinv[row] * (x[row] @ W)), xs packed bf16x2.
// Block = 256 thr = 4 waves; wave w -> rows row0+16w .. +15 (full 128 cols).
// A-frag straight from global fp32 x (convert in reg); B-frag from global Wt.
__global__ __launch_bounds__(256) void k_gemm(const float* __restrict__ x,
                                              const unsigned short* __restrict__ Wt,
                                              const float* __restrict__ dinv,
                                              unsigned* __restrict__ xs_out, int N) {
    __shared__ short out_lds[4][16][136];   // +8 pad breaks quad bank aliasing
    const int t = threadIdx.x;
    const int wv = t >> 6;
    const int lane = t & 63;
    const int quad = lane >> 4;
    const int lid = lane & 15;
    const int row0 = blockIdx.x * 64;

    // A fragments: rows row0+16wv+lid, k = q*32 + quad*8 + j
    int grow = row0 + wv * 16 + lid;
    int growc = grow < N ? grow : N - 1;
    short8 af[4];
#pragma unroll
    for (int q = 0; q < 4; ++q) {
        const float4* xr = (const float4*)(x + (size_t)growc * 128 + q * 32 + quad * 8);
        float4 f0 = xr[0], f1 = xr[1];
        af[q][0] = (short)f2b(f0.x); af[q][1] = (short)f2b(f0.y);
        af[q][2] = (short)f2b(f0.z); af[q][3] = (short)f2b(f0.w);
        af[q][4] = (short)f2b(f1.x); af[q][5] = (short)f2b(f1.y);
        af[q][6] = (short)f2b(f1.z); af[q][7] = (short)f2b(f1.w);
    }

    // dinv for this lane's quad-rows (rows row0+16wv+quad*4 .. +3)
    float4 dv4 = *(const float4*)(dinv + row0 + wv * 16 + quad * 4);

#pragma unroll
    for (int c = 0; c < 8; ++c) {
        f32x4 acc = {0.f, 0.f, 0.f, 0.f};
#pragma unroll
        for (int q = 0; q < 4; ++q) {
            const short8* bp = (const short8*)(Wt + (size_t)(c * 16 + lid) * 128 +
                                               q * 32 + quad * 8);
            acc = __builtin_amdgcn_mfma_f32_16x16x32_bf16(af[q], *bp, acc, 0, 0, 0);
        }
        // D: row=quad*4+r, col=c*16+lid ; apply dinv, stash bf16 in LDS
        out_lds[wv][quad * 4 + 0][c * 16 + lid] = (short)f2b(acc[0] * dv4.x);
        out_lds[wv][quad * 4 + 1][c * 16 + lid] = (short)f2b(acc[1] * dv4.y);
        out_lds[wv][quad * 4 + 2][c * 16 + lid] = (short)f2b(acc[2] * dv4.z);
        out_lds[wv][quad * 4 + 3][c * 16 + lid] = (short)f2b(acc[3] * dv4.w);
    }
    __syncthreads();

    // coalesced writeback: lane covers 64 B of one row
    int rl = lane >> 2;        // local row 0..15
    int cseg = lane & 3;       // 64 B segment
    int grow2 = row0 + wv * 16 + rl;
    if (grow2 < N) {
        uint4* dst = (uint4*)(xs_out + (size_t)grow2 * 64);
        const uint4* srcp = (const uint4*)((const char*)&out_lds[wv][rl][0] + cseg * 64);
#pragma unroll
        for (int tt = 0; tt < 4; ++tt) dst[cseg * 4 + tt] = srcp[tt];
    }
}

// one wave per node; indices cached in a register (lane j = edge j);
// each gather = 8B/lane -> 2 source rows per instruction.
__global__ __launch_bounds__(256) void k_aggregate(const unsigned* __restrict__ xs,
                                                   const int* __restrict__ csr_src,
                                                   const int* __restrict__ rowstart,
                                                   const int* __restrict__ deg,
                                                   const float* __restrict__ dinv,
                                                   const float* __restrict__ bias,
                                                   float* __restrict__ out, int N) {
    const int wave = threadIdx.x >> 6;
    const int lane = threadIdx.x & 63;
    const int n = blockIdx.x * 4 + wave;
    if (n >= N) return;

    const int rs = rowstart[n];
    const int c = deg[n];
    const float dv = dinv[n];
    const int half = lane >> 5;   // which edge of the pair
    const int sub = lane & 31;    // uint2 index: features 4*sub..+3

    // preload up to 64 edge indices, one per lane
    int idxreg = (lane < c) ? csr_src[rs + lane] : n;

    float4 acc = make_float4(0.f, 0.f, 0.f, 0.f);
    const uint2* xsv = (const uint2*)xs;

    int cmain = c < 64 ? c : 64;
    int i = 0;
    for (; i + 16 <= cmain; i += 16) {
#pragma unroll
        for (int j = 0; j < 8; ++j) {
            int row = __shfl(idxreg, i + 2 * j + half);
            uint2 u = xsv[(size_t)row * 32 + sub];
            acc4(acc, u);
        }
    }
    if (i < cmain) {   // masked round (e always < 64 here)
#pragma unroll
        for (int j = 0; j < 8; ++j) {
            int e = i + 2 * j + half;
            int row = __shfl(idxreg, e < 64 ? e : 0);
            uint2 u = xsv[(size_t)row * 32 + sub];
            if (e >= cmain) { u.x = 0u; u.y = 0u; }
            acc4(acc, u);
        }
        i = cmain;
    }
    for (; i < c; i += 2) {   // ultra-rare overflow (deg > 64)
        int e = i + half;
        uint2 u = make_uint2(0u, 0u);
        if (e < c) u = xsv[(size_t)csr_src[rs + e] * 32 + sub];
        acc4(acc, u);
    }

    // fold edge halves
    acc.x += __shfl_xor(acc.x, 32);
    acc.y += __shfl_xor(acc.y, 32);
    acc.z += __shfl_xor(acc.z, 32);
    acc.w += __shfl_xor(acc.w, 32);

    if (lane < 32) {
        uint2 su = xsv[(size_t)n * 32 + lane];   // self-loop term
        acc4(acc, su);
        float4 bb = ((const float4*)bias)[lane];
        float4 o;
        o.x = fmaxf(dv * acc.x + bb.x, 0.f);
        o.y = fmaxf(dv * acc.y + bb.y, 0.f);
        o.z = fmaxf(dv * acc.z + bb.z, 0.f);
        o.w = fmaxf(dv * acc.w + bb.w, 0.f);
        ((float4*)(out + (size_t)n * 128))[lane] = o;
    }
}

extern "C" void kernel_launch(void* const* d_in, const int* in_sizes, int n_in,
                              void* d_out, int out_size, void* d_ws, size_t ws_size,
                              hipStream_t stream) {
    const float* x   = (const float*)d_in[0];
    const int*   ei  = (const int*)d_in[1];     // [2, E] flat: src then dst
    const float* W   = (const float*)d_in[2];
    const float* b   = (const float*)d_in[3];
    float*       out = (float*)d_out;

    const int N = in_sizes[0] / 128;
    const int E = in_sizes[1] / 2;
    const int* src = ei;
    const int* dst = ei + E;

    // workspace carve (256B aligned)
    auto align = [](size_t v) { return (v + 255) & ~(size_t)255; };
    char* p = (char*)d_ws;
    int*            deg      = (int*)p;            p += align((size_t)N * 4);
    int*            rowstart = (int*)p;            p += align((size_t)N * 4);
    int*            bsum     = (int*)p;            p += align(512 * 4);
    float*          dinv     = (float*)p;          p += align((size_t)N * 4);
    int*            rank     = (int*)p;            p += align((size_t)E * 4);
    int*            csr_src  = (int*)p;            p += align((size_t)E * 4);
    unsigned*       xs       = (unsigned*)p;       p += align((size_t)N * 64 * 4);
    unsigned short* Wt       = (unsigned short*)p; p += align(128 * 128 * 2);
    (void)ws_size;

    const int nbN  = (N + 255) / 256;   // 391 (<=512 required by scanB)
    const int nbE4 = (E + 1023) / 1024;

    k_init<<<nbN, 256, 0, stream>>>(deg, N);
    k_count<<<nbE4, 256, 0, stream>>>(dst, deg, rank, E);
    k_scanA<<<nbN, 256, 0, stream>>>(deg, bsum, N);
    k_scanB<<<1, 512, 0, stream>>>(bsum, nbN);
    k_scanC<<<nbN, 256, 0, stream>>>(deg, bsum, rowstart, dinv, N);
    k_fill<<<nbE4, 256, 0, stream>>>(src, dst, rowstart, rank, csr_src, E);
    k_wconv<<<64, 256, 0, stream>>>(W, Wt);
    k_gemm<<<(N + 63) / 64, 256, 0, stream>>>(x, Wt, dinv, xs, N);
    k_aggregate<<<(N + 3) / 4, 256, 0, stream>>>(xs, csr_src, rowstart, deg, dinv, b,
                                                 out, N);
}

// Round 5
// 266.540 us; speedup vs baseline: 1.6628x; 1.1966x over previous
//
#include <hip/hip_runtime.h>
#include <hip/hip_bf16.h>

// GCNConv: out = relu( D^{-1/2} (A + I) D^{-1/2} (x @ W) + b )
// CSR build via atomic-free two-phase bucket sort (bucket = dst>>7, 128 nodes):
//   1. k_hist   : per-block LDS histograms -> hist[bucket][block] (bucket-major)
//   2. scanA/B/C2: exclusive scan of hist -> per-(bucket,block) write bases
//   3. k_scatter: edges -> bucket-grouped packed array (src | dlow<<17)
//   4. k_csr    : per-bucket LDS histogram + scan + LDS-atomic rank ->
//                 csr_src, deg, rowstart, dinv (all full-line writes)
// Then:
//   5. Wt = bf16(W^T)
//   6. xs = bf16( dinv[n] * (x[n] @ W) )  via MFMA 16x16x32 bf16
//   7. out[n] = relu( dinv[n]*(xs[n] + sum_{s in in(n)} xs[s]) + b )

#define SCAN_BLK 256
#define NP1 128          // blocks in phase-1 (hist/scatter)
#define MAXB 1024        // static LDS cap on bucket count (N <= 131072)

typedef short  short8 __attribute__((ext_vector_type(8)));
typedef float  f32x4  __attribute__((ext_vector_type(4)));

__device__ inline unsigned short f2b(float f) {   // fp32 -> bf16 RNE
    unsigned u = __float_as_uint(f);
    return (unsigned short)((u + 0x7fffu + ((u >> 16) & 1u)) >> 16);
}

__device__ inline void acc4(float4& a, uint2 u) {
    a.x += __uint_as_float(u.x << 16);
    a.y += __uint_as_float(u.x & 0xffff0000u);
    a.z += __uint_as_float(u.y << 16);
    a.w += __uint_as_float(u.y & 0xffff0000u);
}

// ---- phase 1: bucket histogram ------------------------------------------
__global__ __launch_bounds__(256) void k_hist(const int* __restrict__ dst,
                                              int* __restrict__ hist,
                                              int E, int B, int chunk) {
    __shared__ int h[MAXB];
    for (int i = threadIdx.x; i < B; i += 256) h[i] = 0;
    __syncthreads();
    int e0 = blockIdx.x * chunk;
    int e1 = min(E, e0 + chunk);
    for (int e = e0 + threadIdx.x; e < e1; e += 256)
        atomicAdd(&h[dst[e] >> 7], 1);
    __syncthreads();
    for (int i = threadIdx.x; i < B; i += 256)
        hist[i * NP1 + blockIdx.x] = h[i];
}

// ---- generic exclusive scan over M ints (scanA -> scanB -> scanC2) ------
__global__ __launch_bounds__(SCAN_BLK) void k_scanA(const int* __restrict__ in,
                                                    int* __restrict__ bsum, int M) {
    __shared__ int s[SCAN_BLK];
    int t = threadIdx.x;
    int i = blockIdx.x * SCAN_BLK + t;
    s[t] = (i < M) ? in[i] : 0;
    __syncthreads();
    for (int off = SCAN_BLK / 2; off > 0; off >>= 1) {
        if (t < off) s[t] += s[t + off];
        __syncthreads();
    }
    if (t == 0) bsum[blockIdx.x] = s[0];
}

__global__ __launch_bounds__(512) void k_scanB(int* __restrict__ bsum, int nb) {
    __shared__ int s[512];
    int t = threadIdx.x;
    int v = (t < nb) ? bsum[t] : 0;
    s[t] = v;
    __syncthreads();
    for (int off = 1; off < 512; off <<= 1) {
        int add = (t >= off) ? s[t - off] : 0;
        __syncthreads();
        s[t] += add;
        __syncthreads();
    }
    if (t < nb) bsum[t] = s[t] - v;   // exclusive
}

__global__ __launch_bounds__(SCAN_BLK) void k_scanC2(const int* __restrict__ in,
                                                     const int* __restrict__ bsum,
                                                     int* __restrict__ outp, int M) {
    __shared__ int s[SCAN_BLK];
    int t = threadIdx.x;
    int i = blockIdx.x * SCAN_BLK + t;
    int v = (i < M) ? in[i] : 0;
    s[t] = v;
    __syncthreads();
    for (int off = 1; off < SCAN_BLK; off <<= 1) {
        int add = (t >= off) ? s[t - off] : 0;
        __syncthreads();
        s[t] += add;
        __syncthreads();
    }
    if (i < M) outp[i] = s[t] - v + bsum[blockIdx.x];
}

// ---- phase 1c: bucket-grouped scatter (LDS cursors, no global atomics) --
__global__ __launch_bounds__(256) void k_scatter(const int* __restrict__ src,
                                                 const int* __restrict__ dst,
                                                 const int* __restrict__ hist_s,
                                                 unsigned* __restrict__ bucketed,
                                                 int E, int B, int chunk) {
    __shared__ int cur[MAXB];
    for (int i = threadIdx.x; i < B; i += 256)
        cur[i] = hist_s[i * NP1 + blockIdx.x];
    __syncthreads();
    int e0 = blockIdx.x * chunk;
    int e1 = min(E, e0 + chunk);
    for (int e = e0 + threadIdx.x; e < e1; e += 256) {
        int d = dst[e];
        int p = atomicAdd(&cur[d >> 7], 1);   // LDS atomic
        bucketed[p] = (unsigned)src[e] | ((unsigned)(d & 127) << 17);
    }
}

// ---- phase 2: per-bucket CSR finalize -----------------------------------
__global__ __launch_bounds__(256) void k_csr(const unsigned* __restrict__ bucketed,
                                             const int* __restrict__ hist_s,
                                             int* __restrict__ csr_src,
                                             int* __restrict__ deg_g,
                                             int* __restrict__ rowstart_g,
                                             float* __restrict__ dinv_g,
                                             int E, int B, int N) {
    const int b = blockIdx.x;
    const int t = threadIdx.x;
    const int base = hist_s[b * NP1];
    const int endv = (b + 1 < B) ? hist_s[(b + 1) * NP1] : E;
    const int cnt = endv - base;
    const int node0 = b << 7;

    __shared__ int sdeg[128], sscan[128], cur[128];
    if (t < 128) sdeg[t] = 0;
    __syncthreads();
    for (int i = t; i < cnt; i += 256)
        atomicAdd(&sdeg[bucketed[base + i] >> 17], 1);
    __syncthreads();
    if (t < 128) sscan[t] = sdeg[t];
    __syncthreads();
    for (int off = 1; off < 128; off <<= 1) {
        int add = 0;
        if (t < 128 && t >= off) add = sscan[t - off];
        __syncthreads();
        if (t < 128) sscan[t] += add;
        __syncthreads();
    }
    if (t < 128) {
        int rs = sscan[t] - sdeg[t];   // exclusive
        cur[t] = rs;
        int node = node0 + t;
        if (node < N) {
            deg_g[node] = sdeg[t];
            rowstart_g[node] = base + rs;
            dinv_g[node] = rsqrtf((float)(sdeg[t] + 1));   // +1 self-loop
        }
    }
    __syncthreads();
    for (int i = t; i < cnt; i += 256) {
        unsigned w = bucketed[base + i];
        int p = atomicAdd(&cur[w >> 17], 1);   // LDS atomic
        csr_src[base + p] = (int)(w & 0x1FFFFu);
    }
}

// ---- Wt[n][k] = bf16(W[k][n]) -------------------------------------------
__global__ __launch_bounds__(256) void k_wconv(const float* __restrict__ W,
                                               unsigned short* __restrict__ Wt) {
    int i = blockIdx.x * 256 + threadIdx.x;   // 0..16383
    int k = i >> 7, n = i & 127;
    Wt[n * 128 + k] = f2b(W[k * 128 + n]);
}

// ---- MFMA gemm: xs = bf16(dinv * (x @ W)), packed bf16x2 ----------------
__global__ __launch_bounds__(256) void k_gemm(const float* __restrict__ x,
                                              const unsigned short* __restrict__ Wt,
                                              const float* __restrict__ dinv,
                                              unsigned* __restrict__ xs_out, int N) {
    __shared__ short out_lds[4][16][136];
    const int t = threadIdx.x;
    const int wv = t >> 6;
    const int lane = t & 63;
    const int quad = lane >> 4;
    const int lid = lane & 15;
    const int row0 = blockIdx.x * 64;

    int grow = row0 + wv * 16 + lid;
    int growc = grow < N ? grow : N - 1;
    short8 af[4];
#pragma unroll
    for (int q = 0; q < 4; ++q) {
        const float4* xr = (const float4*)(x + (size_t)growc * 128 + q * 32 + quad * 8);
        float4 f0 = xr[0], f1 = xr[1];
        af[q][0] = (short)f2b(f0.x); af[q][1] = (short)f2b(f0.y);
        af[q][2] = (short)f2b(f0.z); af[q][3] = (short)f2b(f0.w);
        af[q][4] = (short)f2b(f1.x); af[q][5] = (short)f2b(f1.y);
        af[q][6] = (short)f2b(f1.z); af[q][7] = (short)f2b(f1.w);
    }

    int drow = row0 + wv * 16 + quad * 4;
    float4 dv4;
    if (drow + 3 < N)      dv4 = *(const float4*)(dinv + drow);
    else {
        dv4.x = dinv[min(drow + 0, N - 1)];
        dv4.y = dinv[min(drow + 1, N - 1)];
        dv4.z = dinv[min(drow + 2, N - 1)];
        dv4.w = dinv[min(drow + 3, N - 1)];
    }

#pragma unroll
    for (int c = 0; c < 8; ++c) {
        f32x4 acc = {0.f, 0.f, 0.f, 0.f};
#pragma unroll
        for (int q = 0; q < 4; ++q) {
            const short8* bp = (const short8*)(Wt + (size_t)(c * 16 + lid) * 128 +
                                               q * 32 + quad * 8);
            acc = __builtin_amdgcn_mfma_f32_16x16x32_bf16(af[q], *bp, acc, 0, 0, 0);
        }
        out_lds[wv][quad * 4 + 0][c * 16 + lid] = (short)f2b(acc[0] * dv4.x);
        out_lds[wv][quad * 4 + 1][c * 16 + lid] = (short)f2b(acc[1] * dv4.y);
        out_lds[wv][quad * 4 + 2][c * 16 + lid] = (short)f2b(acc[2] * dv4.z);
        out_lds[wv][quad * 4 + 3][c * 16 + lid] = (short)f2b(acc[3] * dv4.w);
    }
    __syncthreads();

    int rl = lane >> 2;
    int cseg = lane & 3;
    int grow2 = row0 + wv * 16 + rl;
    if (grow2 < N) {
        uint4* dstp = (uint4*)(xs_out + (size_t)grow2 * 64);
        const uint4* srcp = (const uint4*)((const char*)&out_lds[wv][rl][0] + cseg * 64);
#pragma unroll
        for (int tt = 0; tt < 4; ++tt) dstp[cseg * 4 + tt] = srcp[tt];
    }
}

// ---- aggregate: one wave/node, reg-cached indices, 2 rows per gather ----
__global__ __launch_bounds__(256) void k_aggregate(const unsigned* __restrict__ xs,
                                                   const int* __restrict__ csr_src,
                                                   const int* __restrict__ rowstart,
                                                   const int* __restrict__ deg,
                                                   const float* __restrict__ dinv,
                                                   const float* __restrict__ bias,
                                                   float* __restrict__ out, int N) {
    const int wave = threadIdx.x >> 6;
    const int lane = threadIdx.x & 63;
    const int n = blockIdx.x * 4 + wave;
    if (n >= N) return;

    const int rs = rowstart[n];
    const int c = deg[n];
    const float dv = dinv[n];
    const int half = lane >> 5;
    const int sub = lane & 31;

    int idxreg = (lane < c) ? csr_src[rs + lane] : n;

    float4 acc = make_float4(0.f, 0.f, 0.f, 0.f);
    const uint2* xsv = (const uint2*)xs;

    int cmain = c < 64 ? c : 64;
    int i = 0;
    for (; i + 16 <= cmain; i += 16) {
#pragma unroll
        for (int j = 0; j < 8; ++j) {
            int row = __shfl(idxreg, i + 2 * j + half);
            uint2 u = xsv[(size_t)row * 32 + sub];
            acc4(acc, u);
        }
    }
    if (i < cmain) {
#pragma unroll
        for (int j = 0; j < 8; ++j) {
            int e = i + 2 * j + half;
            int row = __shfl(idxreg, e < 64 ? e : 0);
            uint2 u = xsv[(size_t)row * 32 + sub];
            if (e >= cmain) { u.x = 0u; u.y = 0u; }
            acc4(acc, u);
        }
        i = cmain;
    }
    for (; i < c; i += 2) {   // rare deg > 64 tail
        int e = i + half;
        uint2 u = make_uint2(0u, 0u);
        if (e < c) u = xsv[(size_t)csr_src[rs + e] * 32 + sub];
        acc4(acc, u);
    }

    acc.x += __shfl_xor(acc.x, 32);
    acc.y += __shfl_xor(acc.y, 32);
    acc.z += __shfl_xor(acc.z, 32);
    acc.w += __shfl_xor(acc.w, 32);

    if (lane < 32) {
        uint2 su = xsv[(size_t)n * 32 + lane];   // self-loop
        acc4(acc, su);
        float4 bb = ((const float4*)bias)[lane];
        float4 o;
        o.x = fmaxf(dv * acc.x + bb.x, 0.f);
        o.y = fmaxf(dv * acc.y + bb.y, 0.f);
        o.z = fmaxf(dv * acc.z + bb.z, 0.f);
        o.w = fmaxf(dv * acc.w + bb.w, 0.f);
        ((float4*)(out + (size_t)n * 128))[lane] = o;
    }
}

extern "C" void kernel_launch(void* const* d_in, const int* in_sizes, int n_in,
                              void* d_out, int out_size, void* d_ws, size_t ws_size,
                              hipStream_t stream) {
    const float* x   = (const float*)d_in[0];
    const int*   ei  = (const int*)d_in[1];     // [2, E] flat: src then dst
    const float* W   = (const float*)d_in[2];
    const float* b   = (const float*)d_in[3];
    float*       out = (float*)d_out;

    const int N = in_sizes[0] / 128;
    const int E = in_sizes[1] / 2;
    const int* src = ei;
    const int* dst = ei + E;

    const int B = (N + 127) >> 7;            // 782 buckets
    const int M = B * NP1;                   // 100,096 scan entries
    const int chunk = (E + NP1 - 1) / NP1;   // 12,500 edges per phase-1 block

    // workspace carve (256B aligned)
    auto align = [](size_t v) { return (v + 255) & ~(size_t)255; };
    char* p = (char*)d_ws;
    int*            hist     = (int*)p;            p += align((size_t)M * 4);
    int*            hist_s   = (int*)p;            p += align((size_t)M * 4);
    int*            bsum     = (int*)p;            p += align(512 * 4);
    int*            deg      = (int*)p;            p += align((size_t)N * 4);
    int*            rowstart = (int*)p;            p += align((size_t)N * 4);
    float*          dinv     = (float*)p;          p += align((size_t)N * 4);
    unsigned*       bucketed = (unsigned*)p;       p += align((size_t)E * 4);
    int*            csr_src  = (int*)p;            p += align((size_t)E * 4);
    unsigned*       xs       = (unsigned*)p;       p += align((size_t)N * 64 * 4);
    unsigned short* Wt       = (unsigned short*)p; p += align(128 * 128 * 2);
    (void)ws_size;

    const int nbM = (M + SCAN_BLK - 1) / SCAN_BLK;   // 392 (<=512 for scanB)

    k_hist   <<<NP1, 256, 0, stream>>>(dst, hist, E, B, chunk);
    k_scanA  <<<nbM, 256, 0, stream>>>(hist, bsum, M);
    k_scanB  <<<1, 512, 0, stream>>>(bsum, nbM);
    k_scanC2 <<<nbM, 256, 0, stream>>>(hist, bsum, hist_s, M);
    k_scatter<<<NP1, 256, 0, stream>>>(src, dst, hist_s, bucketed, E, B, chunk);
    k_csr    <<<B, 256, 0, stream>>>(bucketed, hist_s, csr_src, deg, rowstart, dinv,
                                     E, B, N);
    k_wconv  <<<64, 256, 0, stream>>>(W, Wt);
    k_gemm   <<<(N + 63) / 64, 256, 0, stream>>>(x, Wt, dinv, xs, N);
    k_aggregate<<<(N + 3) / 4, 256, 0, stream>>>(xs, csr_src, rowstart, deg, dinv, b,
                                                 out, N);
}

// Round 6
// 261.657 us; speedup vs baseline: 1.6939x; 1.0187x over previous
//
#include <hip/hip_runtime.h>
#include <hip/hip_bf16.h>

// GCNConv: out = relu( D^{-1/2} (A + I) D^{-1/2} (x @ W) + b )
// CSR build via atomic-free two-phase bucket sort (bucket = dst>>7):
//   1. k_hist   : per-block LDS histograms -> hist[bucket][block] (+ Wt convert)
//   2. scanA/B/C2: exclusive scan of hist (in place) -> write bases
//   3. k_scatter: edges -> bucket-grouped packed array (src | dlow<<17)
//   4. k_csr    : per-bucket LDS hist+scan+rank -> csr_src, rowptr[N+1], dinv
//   5. k_gemm   : xs = bf16( dinv[n] * (x[n] @ W) )  via MFMA 16x16x32 bf16
//   6. k_aggregate: 4 nodes/wave, prefetched indices, uint4 gathers
//                   (4 rows/instr), coalesced 512B epilogue store

#define SCAN_BLK 256
#define NP1 128          // blocks in phase-1 (hist/scatter)
#define MAXB 1024        // static LDS cap on bucket count (N <= 131072)

typedef short  short8 __attribute__((ext_vector_type(8)));
typedef float  f32x4  __attribute__((ext_vector_type(4)));

__device__ inline unsigned short f2b(float f) {   // fp32 -> bf16 RNE
    unsigned u = __float_as_uint(f);
    return (unsigned short)((u + 0x7fffu + ((u >> 16) & 1u)) >> 16);
}

__device__ inline void acc4(float4& a, unsigned lo, unsigned hi) {
    a.x += __uint_as_float(lo << 16);
    a.y += __uint_as_float(lo & 0xffff0000u);
    a.z += __uint_as_float(hi << 16);
    a.w += __uint_as_float(hi & 0xffff0000u);
}

// ---- phase 1: bucket histogram (+ fused Wt = bf16(W^T)) -----------------
__global__ __launch_bounds__(256) void k_hist(const int* __restrict__ dst,
                                              int* __restrict__ hist,
                                              const float* __restrict__ W,
                                              unsigned short* __restrict__ Wt,
                                              int E, int B, int chunk) {
    __shared__ int h[MAXB];
    for (int i = threadIdx.x; i < B; i += 256) h[i] = 0;
    __syncthreads();
    int e0 = blockIdx.x * chunk;
    int e1 = min(E, e0 + chunk);
    for (int e = e0 + threadIdx.x; e < e1; e += 256)
        atomicAdd(&h[dst[e] >> 7], 1);
    __syncthreads();
    for (int i = threadIdx.x; i < B; i += 256)
        hist[i * NP1 + blockIdx.x] = h[i];
    if (blockIdx.x < 64) {                      // fused weight transpose
        int i = blockIdx.x * 256 + threadIdx.x; // 0..16383
        int k = i >> 7, n = i & 127;
        Wt[n * 128 + k] = f2b(W[k * 128 + n]);
    }
}

// ---- generic exclusive scan over M ints ---------------------------------
__global__ __launch_bounds__(SCAN_BLK) void k_scanA(const int* __restrict__ in,
                                                    int* __restrict__ bsum, int M) {
    __shared__ int s[SCAN_BLK];
    int t = threadIdx.x;
    int i = blockIdx.x * SCAN_BLK + t;
    s[t] = (i < M) ? in[i] : 0;
    __syncthreads();
    for (int off = SCAN_BLK / 2; off > 0; off >>= 1) {
        if (t < off) s[t] += s[t + off];
        __syncthreads();
    }
    if (t == 0) bsum[blockIdx.x] = s[0];
}

__global__ __launch_bounds__(512) void k_scanB(int* __restrict__ bsum, int nb) {
    __shared__ int s[512];
    int t = threadIdx.x;
    int v = (t < nb) ? bsum[t] : 0;
    s[t] = v;
    __syncthreads();
    for (int off = 1; off < 512; off <<= 1) {
        int add = (t >= off) ? s[t - off] : 0;
        __syncthreads();
        s[t] += add;
        __syncthreads();
    }
    if (t < nb) bsum[t] = s[t] - v;   // exclusive
}

// in-place safe: each element read+written only by its own block
__global__ __launch_bounds__(SCAN_BLK) void k_scanC2(int* __restrict__ data,
                                                     const int* __restrict__ bsum,
                                                     int M) {
    __shared__ int s[SCAN_BLK];
    int t = threadIdx.x;
    int i = blockIdx.x * SCAN_BLK + t;
    int v = (i < M) ? data[i] : 0;
    s[t] = v;
    __syncthreads();
    for (int off = 1; off < SCAN_BLK; off <<= 1) {
        int add = (t >= off) ? s[t - off] : 0;
        __syncthreads();
        s[t] += add;
        __syncthreads();
    }
    if (i < M) data[i] = s[t] - v + bsum[blockIdx.x];
}

// ---- phase 1c: bucket-grouped scatter (LDS cursors) ---------------------
__global__ __launch_bounds__(256) void k_scatter(const int* __restrict__ src,
                                                 const int* __restrict__ dst,
                                                 const int* __restrict__ hist_s,
                                                 unsigned* __restrict__ bucketed,
                                                 int E, int B, int chunk) {
    __shared__ int cur[MAXB];
    for (int i = threadIdx.x; i < B; i += 256)
        cur[i] = hist_s[i * NP1 + blockIdx.x];
    __syncthreads();
    int e0 = blockIdx.x * chunk;
    int e1 = min(E, e0 + chunk);
    for (int e = e0 + threadIdx.x; e < e1; e += 256) {
        int d = dst[e];
        int p = atomicAdd(&cur[d >> 7], 1);   // LDS atomic
        bucketed[p] = (unsigned)src[e] | ((unsigned)(d & 127) << 17);
    }
}

// ---- phase 2: per-bucket CSR finalize -----------------------------------
__global__ __launch_bounds__(256) void k_csr(const unsigned* __restrict__ bucketed,
                                             const int* __restrict__ hist_s,
                                             int* __restrict__ csr_src,
                                             int* __restrict__ rowptr,   // N+1
                                             float* __restrict__ dinv_g,
                                             int E, int B, int N) {
    const int b = blockIdx.x;
    const int t = threadIdx.x;
    const int base = hist_s[b * NP1];
    const int endv = (b + 1 < B) ? hist_s[(b + 1) * NP1] : E;
    const int cnt = endv - base;
    const int node0 = b << 7;

    __shared__ int sdeg[128], sscan[128], cur[128];
    if (t < 128) sdeg[t] = 0;
    __syncthreads();
    for (int i = t; i < cnt; i += 256)
        atomicAdd(&sdeg[bucketed[base + i] >> 17], 1);
    __syncthreads();
    if (t < 128) sscan[t] = sdeg[t];
    __syncthreads();
    for (int off = 1; off < 128; off <<= 1) {
        int add = 0;
        if (t < 128 && t >= off) add = sscan[t - off];
        __syncthreads();
        if (t < 128) sscan[t] += add;
        __syncthreads();
    }
    if (t < 128) {
        int rs = sscan[t] - sdeg[t];   // exclusive
        cur[t] = rs;
        int node = node0 + t;
        if (node < N) {
            rowptr[node] = base + rs;
            dinv_g[node] = rsqrtf((float)(sdeg[t] + 1));   // +1 self-loop
        }
    }
    if (b == B - 1 && t == 0) rowptr[N] = E;
    __syncthreads();
    for (int i = t; i < cnt; i += 256) {
        unsigned w = bucketed[base + i];
        int p = atomicAdd(&cur[w >> 17], 1);   // LDS atomic
        csr_src[base + p] = (int)(w & 0x1FFFFu);
    }
}

// ---- MFMA gemm: xs = bf16(dinv * (x @ W)), packed bf16x2 ----------------
__global__ __launch_bounds__(256) void k_gemm(const float* __restrict__ x,
                                              const unsigned short* __restrict__ Wt,
                                              const float* __restrict__ dinv,
                                              unsigned* __restrict__ xs_out, int N) {
    __shared__ short out_lds[4][16][136];
    const int t = threadIdx.x;
    const int wv = t >> 6;
    const int lane = t & 63;
    const int quad = lane >> 4;
    const int lid = lane & 15;
    const int row0 = blockIdx.x * 64;

    int grow = row0 + wv * 16 + lid;
    int growc = grow < N ? grow : N - 1;
    short8 af[4];
#pragma unroll
    for (int q = 0; q < 4; ++q) {
        const float4* xr = (const float4*)(x + (size_t)growc * 128 + q * 32 + quad * 8);
        float4 f0 = xr[0], f1 = xr[1];
        af[q][0] = (short)f2b(f0.x); af[q][1] = (short)f2b(f0.y);
        af[q][2] = (short)f2b(f0.z); af[q][3] = (short)f2b(f0.w);
        af[q][4] = (short)f2b(f1.x); af[q][5] = (short)f2b(f1.y);
        af[q][6] = (short)f2b(f1.z); af[q][7] = (short)f2b(f1.w);
    }

    int drow = row0 + wv * 16 + quad * 4;
    float4 dv4;
    if (drow + 3 < N)      dv4 = *(const float4*)(dinv + drow);
    else {
        dv4.x = dinv[min(drow + 0, N - 1)];
        dv4.y = dinv[min(drow + 1, N - 1)];
        dv4.z = dinv[min(drow + 2, N - 1)];
        dv4.w = dinv[min(drow + 3, N - 1)];
    }

#pragma unroll
    for (int c = 0; c < 8; ++c) {
        f32x4 acc = {0.f, 0.f, 0.f, 0.f};
#pragma unroll
        for (int q = 0; q < 4; ++q) {
            const short8* bp = (const short8*)(Wt + (size_t)(c * 16 + lid) * 128 +
                                               q * 32 + quad * 8);
            acc = __builtin_amdgcn_mfma_f32_16x16x32_bf16(af[q], *bp, acc, 0, 0, 0);
        }
        out_lds[wv][quad * 4 + 0][c * 16 + lid] = (short)f2b(acc[0] * dv4.x);
        out_lds[wv][quad * 4 + 1][c * 16 + lid] = (short)f2b(acc[1] * dv4.y);
        out_lds[wv][quad * 4 + 2][c * 16 + lid] = (short)f2b(acc[2] * dv4.z);
        out_lds[wv][quad * 4 + 3][c * 16 + lid] = (short)f2b(acc[3] * dv4.w);
    }
    __syncthreads();

    int rl = lane >> 2;
    int cseg = lane & 3;
    int grow2 = row0 + wv * 16 + rl;
    if (grow2 < N) {
        uint4* dstp = (uint4*)(xs_out + (size_t)grow2 * 64);
        const uint4* srcp = (const uint4*)((const char*)&out_lds[wv][rl][0] + cseg * 64);
#pragma unroll
        for (int tt = 0; tt < 4; ++tt) dstp[cseg * 4 + tt] = srcp[tt];
    }
}

// ---- aggregate: 4 nodes/wave, prefetched indices, uint4 gathers ---------
// lane split: grp = lane>>4 (edge slot 0..3), sub = lane&15 (uint4 of row).
// One gather instruction = 4 source rows (64 lanes x 16 B).
__global__ __launch_bounds__(256) void k_aggregate(const uint4* __restrict__ xs4,
                                                   const int* __restrict__ csr_src,
                                                   const int* __restrict__ rowptr,
                                                   const float* __restrict__ dinv,
                                                   const float* __restrict__ bias,
                                                   float* __restrict__ out, int N) {
    const int wave = threadIdx.x >> 6;
    const int lane = threadIdx.x & 63;
    const int g0 = (blockIdx.x * 4 + wave) * 4;
    if (g0 >= N) return;
    const int grp = lane >> 4;
    const int sub = lane & 15;

    // meta: rowptr[g0..g0+4] via lanes 0..4, dinv[g0..g0+3] via lanes 0..3
    int   rp  = rowptr[min(g0 + min(lane, 4), N)];
    float dvl = dinv[min(g0 + min(lane, 3), N - 1)];

    int rs[4], c[4], idx[4];
#pragma unroll
    for (int k = 0; k < 4; ++k) {
        rs[k] = __shfl(rp, k);
        c[k]  = __shfl(rp, k + 1) - rs[k];
    }
#pragma unroll
    for (int k = 0; k < 4; ++k)   // all 4 index vectors in flight before gathers
        idx[k] = (lane < c[k]) ? csr_src[rs[k] + lane] : 0;

    const uint2* xs2 = (const uint2*)xs4;

#pragma unroll
    for (int k = 0; k < 4; ++k) {
        int n = g0 + k;
        if (n < N) {
            const int cc = c[k];
            float4 a0 = make_float4(0.f, 0.f, 0.f, 0.f);
            float4 a1 = make_float4(0.f, 0.f, 0.f, 0.f);
            int cmain = cc < 64 ? cc : 64;
            int jmax = (cmain + 3) >> 2;
            for (int j = 0; j < jmax; ++j) {
                int e = j * 4 + grp;
                int row = __shfl(idx[k], e & 63);
                uint4 u = xs4[(size_t)row * 16 + sub];
                if (e >= cc) { u.x = 0u; u.y = 0u; u.z = 0u; u.w = 0u; }
                acc4(a0, u.x, u.y);
                acc4(a1, u.z, u.w);
            }
            for (int e0 = 64; e0 < cc; e0 += 4) {   // rare deg > 64 tail
                int e = e0 + grp;
                uint4 u = make_uint4(0u, 0u, 0u, 0u);
                if (e < cc) {
                    int row = csr_src[rs[k] + e];
                    u = xs4[(size_t)row * 16 + sub];
                }
                acc4(a0, u.x, u.y);
                acc4(a1, u.z, u.w);
            }
            // fold across the 4 edge slots
            a0.x += __shfl_xor(a0.x, 16); a0.x += __shfl_xor(a0.x, 32);
            a0.y += __shfl_xor(a0.y, 16); a0.y += __shfl_xor(a0.y, 32);
            a0.z += __shfl_xor(a0.z, 16); a0.z += __shfl_xor(a0.z, 32);
            a0.w += __shfl_xor(a0.w, 16); a0.w += __shfl_xor(a0.w, 32);
            a1.x += __shfl_xor(a1.x, 16); a1.x += __shfl_xor(a1.x, 32);
            a1.y += __shfl_xor(a1.y, 16); a1.y += __shfl_xor(a1.y, 32);
            a1.z += __shfl_xor(a1.z, 16); a1.z += __shfl_xor(a1.z, 32);
            a1.w += __shfl_xor(a1.w, 16); a1.w += __shfl_xor(a1.w, 32);

            if (lane < 32) {       // one coalesced 512 B store
                int p = lane >> 4;                 // float4 half: 0 or 1
                int f4 = (lane & 15) * 2 + p;      // float4 index 0..31
                float4 av = p ? a1 : a0;
                uint2 su = xs2[(size_t)n * 32 + f4];   // self-loop (4 bf16)
                acc4(av, su.x, su.y);
                float dv = __shfl(dvl, k);
                float4 bb = ((const float4*)bias)[f4];
                float4 o;
                o.x = fmaxf(dv * av.x + bb.x, 0.f);
                o.y = fmaxf(dv * av.y + bb.y, 0.f);
                o.z = fmaxf(dv * av.z + bb.z, 0.f);
                o.w = fmaxf(dv * av.w + bb.w, 0.f);
                ((float4*)(out + (size_t)n * 128))[f4] = o;
            }
        }
    }
}

extern "C" void kernel_launch(void* const* d_in, const int* in_sizes, int n_in,
                              void* d_out, int out_size, void* d_ws, size_t ws_size,
                              hipStream_t stream) {
    const float* x   = (const float*)d_in[0];
    const int*   ei  = (const int*)d_in[1];     // [2, E] flat: src then dst
    const float* W   = (const float*)d_in[2];
    const float* b   = (const float*)d_in[3];
    float*       out = (float*)d_out;

    const int N = in_sizes[0] / 128;
    const int E = in_sizes[1] / 2;
    const int* src = ei;
    const int* dst = ei + E;

    const int B = (N + 127) >> 7;            // 782 buckets
    const int M = B * NP1;                   // scan entries
    const int chunk = (E + NP1 - 1) / NP1;   // edges per phase-1 block

    // workspace carve (256B aligned)
    auto align = [](size_t v) { return (v + 255) & ~(size_t)255; };
    char* p = (char*)d_ws;
    int*            hist     = (int*)p;            p += align((size_t)M * 4);
    int*            bsum     = (int*)p;            p += align(512 * 4);
    int*            rowptr   = (int*)p;            p += align(((size_t)N + 1) * 4);
    float*          dinv     = (float*)p;          p += align((size_t)N * 4);
    unsigned*       bucketed = (unsigned*)p;       p += align((size_t)E * 4);
    int*            csr_src  = (int*)p;            p += align((size_t)E * 4);
    unsigned*       xs       = (unsigned*)p;       p += align((size_t)N * 64 * 4);
    unsigned short* Wt       = (unsigned short*)p; p += align(128 * 128 * 2);
    (void)ws_size;

    const int nbM = (M + SCAN_BLK - 1) / SCAN_BLK;   // <=512 for scanB

    k_hist   <<<NP1, 256, 0, stream>>>(dst, hist, W, Wt, E, B, chunk);
    k_scanA  <<<nbM, 256, 0, stream>>>(hist, bsum, M);
    k_scanB  <<<1, 512, 0, stream>>>(bsum, nbM);
    k_scanC2 <<<nbM, 256, 0, stream>>>(hist, bsum, M);
    k_scatter<<<NP1, 256, 0, stream>>>(src, dst, hist, bucketed, E, B, chunk);
    k_csr    <<<B, 256, 0, stream>>>(bucketed, hist, csr_src, rowptr, dinv, E, B, N);
    k_gemm   <<<(N + 63) / 64, 256, 0, stream>>>(x, Wt, dinv, xs, N);
    k_aggregate<<<(N + 15) / 16, 256, 0, stream>>>((const uint4*)xs, csr_src, rowptr,
                                                   dinv, b, out, N);
}

// Round 7
// 255.816 us; speedup vs baseline: 1.7325x; 1.0228x over previous
//
#include <hip/hip_runtime.h>
#include <hip/hip_bf16.h>

// GCNConv: out = relu( D^{-1/2} (A + I) D^{-1/2} (x @ W) + b )
// CSR build via atomic-free two-phase bucket sort (bucket = dst>>7):
//   1. k_hist   : per-block LDS histograms -> hist[bucket][block] (+ Wt convert)
//   2. scanA/B/C2: exclusive scan of hist (in place) -> write bases
//   3. k_scatter: edges -> bucket-grouped packed array (src | dlow<<17)
//   4. k_csr    : per-bucket LDS hist+scan+rank -> csr_src, rowptr[N+1], dinv
//   5. k_gemm   : xs = bf16( dinv[n] * (x[n] @ W) )  via MFMA 16x16x32 bf16
//   6. k_aggregate: 1 node/wave, reg-cached indices, uint4 gathers
//                   (4 rows/instr), 4 gathers in flight per round

#define SCAN_BLK 256
#define NP1 128          // blocks in phase-1 (hist/scatter)
#define MAXB 1024        // static LDS cap on bucket count (N <= 131072)

typedef short  short8 __attribute__((ext_vector_type(8)));
typedef float  f32x4  __attribute__((ext_vector_type(4)));

__device__ inline unsigned short f2b(float f) {   // fp32 -> bf16 RNE
    unsigned u = __float_as_uint(f);
    return (unsigned short)((u + 0x7fffu + ((u >> 16) & 1u)) >> 16);
}

__device__ inline void acc4(float4& a, unsigned lo, unsigned hi) {
    a.x += __uint_as_float(lo << 16);
    a.y += __uint_as_float(lo & 0xffff0000u);
    a.z += __uint_as_float(hi << 16);
    a.w += __uint_as_float(hi & 0xffff0000u);
}

// ---- phase 1: bucket histogram (+ fused Wt = bf16(W^T)) -----------------
__global__ __launch_bounds__(256) void k_hist(const int* __restrict__ dst,
                                              int* __restrict__ hist,
                                              const float* __restrict__ W,
                                              unsigned short* __restrict__ Wt,
                                              int E, int B, int chunk) {
    __shared__ int h[MAXB];
    for (int i = threadIdx.x; i < B; i += 256) h[i] = 0;
    __syncthreads();
    int e0 = blockIdx.x * chunk;
    int e1 = min(E, e0 + chunk);
    for (int e = e0 + threadIdx.x; e < e1; e += 256)
        atomicAdd(&h[dst[e] >> 7], 1);
    __syncthreads();
    for (int i = threadIdx.x; i < B; i += 256)
        hist[i * NP1 + blockIdx.x] = h[i];
    if (blockIdx.x < 64) {                      // fused weight transpose
        int i = blockIdx.x * 256 + threadIdx.x; // 0..16383
        int k = i >> 7, n = i & 127;
        Wt[n * 128 + k] = f2b(W[k * 128 + n]);
    }
}

// ---- generic exclusive scan over M ints ---------------------------------
__global__ __launch_bounds__(SCAN_BLK) void k_scanA(const int* __restrict__ in,
                                                    int* __restrict__ bsum, int M) {
    __shared__ int s[SCAN_BLK];
    int t = threadIdx.x;
    int i = blockIdx.x * SCAN_BLK + t;
    s[t] = (i < M) ? in[i] : 0;
    __syncthreads();
    for (int off = SCAN_BLK / 2; off > 0; off >>= 1) {
        if (t < off) s[t] += s[t + off];
        __syncthreads();
    }
    if (t == 0) bsum[blockIdx.x] = s[0];
}

__global__ __launch_bounds__(512) void k_scanB(int* __restrict__ bsum, int nb) {
    __shared__ int s[512];
    int t = threadIdx.x;
    int v = (t < nb) ? bsum[t] : 0;
    s[t] = v;
    __syncthreads();
    for (int off = 1; off < 512; off <<= 1) {
        int add = (t >= off) ? s[t - off] : 0;
        __syncthreads();
        s[t] += add;
        __syncthreads();
    }
    if (t < nb) bsum[t] = s[t] - v;   // exclusive
}

// in-place safe: each element read+written only by its own block
__global__ __launch_bounds__(SCAN_BLK) void k_scanC2(int* __restrict__ data,
                                                     const int* __restrict__ bsum,
                                                     int M) {
    __shared__ int s[SCAN_BLK];
    int t = threadIdx.x;
    int i = blockIdx.x * SCAN_BLK + t;
    int v = (i < M) ? data[i] : 0;
    s[t] = v;
    __syncthreads();
    for (int off = 1; off < SCAN_BLK; off <<= 1) {
        int add = (t >= off) ? s[t - off] : 0;
        __syncthreads();
        s[t] += add;
        __syncthreads();
    }
    if (i < M) data[i] = s[t] - v + bsum[blockIdx.x];
}

// ---- phase 1c: bucket-grouped scatter (LDS cursors) ---------------------
__global__ __launch_bounds__(256) void k_scatter(const int* __restrict__ src,
                                                 const int* __restrict__ dst,
                                                 const int* __restrict__ hist_s,
                                                 unsigned* __restrict__ bucketed,
                                                 int E, int B, int chunk) {
    __shared__ int cur[MAXB];
    for (int i = threadIdx.x; i < B; i += 256)
        cur[i] = hist_s[i * NP1 + blockIdx.x];
    __syncthreads();
    int e0 = blockIdx.x * chunk;
    int e1 = min(E, e0 + chunk);
    for (int e = e0 + threadIdx.x; e < e1; e += 256) {
        int d = dst[e];
        int p = atomicAdd(&cur[d >> 7], 1);   // LDS atomic
        bucketed[p] = (unsigned)src[e] | ((unsigned)(d & 127) << 17);
    }
}

// ---- phase 2: per-bucket CSR finalize -----------------------------------
__global__ __launch_bounds__(256) void k_csr(const unsigned* __restrict__ bucketed,
                                             const int* __restrict__ hist_s,
                                             int* __restrict__ csr_src,
                                             int* __restrict__ rowptr,   // N+1
                                             float* __restrict__ dinv_g,
                                             int E, int B, int N) {
    const int b = blockIdx.x;
    const int t = threadIdx.x;
    const int base = hist_s[b * NP1];
    const int endv = (b + 1 < B) ? hist_s[(b + 1) * NP1] : E;
    const int cnt = endv - base;
    const int node0 = b << 7;

    __shared__ int sdeg[128], sscan[128], cur[128];
    if (t < 128) sdeg[t] = 0;
    __syncthreads();
    for (int i = t; i < cnt; i += 256)
        atomicAdd(&sdeg[bucketed[base + i] >> 17], 1);
    __syncthreads();
    if (t < 128) sscan[t] = sdeg[t];
    __syncthreads();
    for (int off = 1; off < 128; off <<= 1) {
        int add = 0;
        if (t < 128 && t >= off) add = sscan[t - off];
        __syncthreads();
        if (t < 128) sscan[t] += add;
        __syncthreads();
    }
    if (t < 128) {
        int rs = sscan[t] - sdeg[t];   // exclusive
        cur[t] = rs;
        int node = node0 + t;
        if (node < N) {
            rowptr[node] = base + rs;
            dinv_g[node] = rsqrtf((float)(sdeg[t] + 1));   // +1 self-loop
        }
    }
    if (b == B - 1 && t == 0) rowptr[N] = E;
    __syncthreads();
    for (int i = t; i < cnt; i += 256) {
        unsigned w = bucketed[base + i];
        int p = atomicAdd(&cur[w >> 17], 1);   // LDS atomic
        csr_src[base + p] = (int)(w & 0x1FFFFu);
    }
}

// ---- MFMA gemm: xs = bf16(dinv * (x @ W)), packed bf16x2 ----------------
__global__ __launch_bounds__(256) void k_gemm(const float* __restrict__ x,
                                              const unsigned short* __restrict__ Wt,
                                              const float* __restrict__ dinv,
                                              unsigned* __restrict__ xs_out, int N) {
    __shared__ short out_lds[4][16][136];
    const int t = threadIdx.x;
    const int wv = t >> 6;
    const int lane = t & 63;
    const int quad = lane >> 4;
    const int lid = lane & 15;
    const int row0 = blockIdx.x * 64;

    int grow = row0 + wv * 16 + lid;
    int growc = grow < N ? grow : N - 1;
    short8 af[4];
#pragma unroll
    for (int q = 0; q < 4; ++q) {
        const float4* xr = (const float4*)(x + (size_t)growc * 128 + q * 32 + quad * 8);
        float4 f0 = xr[0], f1 = xr[1];
        af[q][0] = (short)f2b(f0.x); af[q][1] = (short)f2b(f0.y);
        af[q][2] = (short)f2b(f0.z); af[q][3] = (short)f2b(f0.w);
        af[q][4] = (short)f2b(f1.x); af[q][5] = (short)f2b(f1.y);
        af[q][6] = (short)f2b(f1.z); af[q][7] = (short)f2b(f1.w);
    }

    int drow = row0 + wv * 16 + quad * 4;
    float4 dv4;
    if (drow + 3 < N)      dv4 = *(const float4*)(dinv + drow);
    else {
        dv4.x = dinv[min(drow + 0, N - 1)];
        dv4.y = dinv[min(drow + 1, N - 1)];
        dv4.z = dinv[min(drow + 2, N - 1)];
        dv4.w = dinv[min(drow + 3, N - 1)];
    }

#pragma unroll
    for (int c = 0; c < 8; ++c) {
        f32x4 acc = {0.f, 0.f, 0.f, 0.f};
#pragma unroll
        for (int q = 0; q < 4; ++q) {
            const short8* bp = (const short8*)(Wt + (size_t)(c * 16 + lid) * 128 +
                                               q * 32 + quad * 8);
            acc = __builtin_amdgcn_mfma_f32_16x16x32_bf16(af[q], *bp, acc, 0, 0, 0);
        }
        out_lds[wv][quad * 4 + 0][c * 16 + lid] = (short)f2b(acc[0] * dv4.x);
        out_lds[wv][quad * 4 + 1][c * 16 + lid] = (short)f2b(acc[1] * dv4.y);
        out_lds[wv][quad * 4 + 2][c * 16 + lid] = (short)f2b(acc[2] * dv4.z);
        out_lds[wv][quad * 4 + 3][c * 16 + lid] = (short)f2b(acc[3] * dv4.w);
    }
    __syncthreads();

    int rl = lane >> 2;
    int cseg = lane & 3;
    int grow2 = row0 + wv * 16 + rl;
    if (grow2 < N) {
        uint4* dstp = (uint4*)(xs_out + (size_t)grow2 * 64);
        const uint4* srcp = (const uint4*)((const char*)&out_lds[wv][rl][0] + cseg * 64);
#pragma unroll
        for (int tt = 0; tt < 4; ++tt) dstp[cseg * 4 + tt] = srcp[tt];
    }
}

// ---- aggregate: 1 node/wave, reg-cached indices, uint4 gathers ----------
// lane split: grp = lane>>4 (edge slot 0..3), sub = lane&15 (uint4 of row).
// One gather instruction = 4 source rows; 4 gathers issued per round.
__global__ __launch_bounds__(256) void k_aggregate(const uint4* __restrict__ xs4,
                                                   const int* __restrict__ csr_src,
                                                   const int* __restrict__ rowptr,
                                                   const float* __restrict__ dinv,
                                                   const float* __restrict__ bias,
                                                   float* __restrict__ out, int N) {
    const int wave = threadIdx.x >> 6;
    const int lane = threadIdx.x & 63;
    const int n = blockIdx.x * 4 + wave;
    if (n >= N) return;
    const int grp = lane >> 4;
    const int sub = lane & 15;

    const int rs = rowptr[n];
    const int c  = rowptr[n + 1] - rs;
    const float dv = dinv[n];

    // preload up to 64 edge indices, one per lane
    int idxreg = (lane < c) ? csr_src[rs + lane] : 0;

    float4 a0 = make_float4(0.f, 0.f, 0.f, 0.f);
    float4 a1 = make_float4(0.f, 0.f, 0.f, 0.f);
    const int cmain = c < 64 ? c : 64;

    int i = 0;
    for (; i + 16 <= cmain; i += 16) {   // unmasked rounds: 4 gathers in flight
#pragma unroll
        for (int j = 0; j < 4; ++j) {
            int row = __shfl(idxreg, i + 4 * j + grp);
            uint4 u = xs4[(size_t)row * 16 + sub];
            acc4(a0, u.x, u.y);
            acc4(a1, u.z, u.w);
        }
    }
    if (i < cmain) {                     // masked round (e <= 63 guaranteed)
#pragma unroll
        for (int j = 0; j < 4; ++j) {
            int e = i + 4 * j + grp;
            int row = __shfl(idxreg, e);
            uint4 u = xs4[(size_t)row * 16 + sub];
            if (e >= cmain) { u.x = 0u; u.y = 0u; u.z = 0u; u.w = 0u; }
            acc4(a0, u.x, u.y);
            acc4(a1, u.z, u.w);
        }
    }
    for (int e0 = 64; e0 < c; e0 += 4) { // rare deg > 64 tail
        int e = e0 + grp;
        uint4 u = make_uint4(0u, 0u, 0u, 0u);
        if (e < c) {
            int row = csr_src[rs + e];
            u = xs4[(size_t)row * 16 + sub];
        }
        acc4(a0, u.x, u.y);
        acc4(a1, u.z, u.w);
    }

    // fold across the 4 edge slots (lane bits 4 and 5)
    a0.x += __shfl_xor(a0.x, 16); a0.x += __shfl_xor(a0.x, 32);
    a0.y += __shfl_xor(a0.y, 16); a0.y += __shfl_xor(a0.y, 32);
    a0.z += __shfl_xor(a0.z, 16); a0.z += __shfl_xor(a0.z, 32);
    a0.w += __shfl_xor(a0.w, 16); a0.w += __shfl_xor(a0.w, 32);
    a1.x += __shfl_xor(a1.x, 16); a1.x += __shfl_xor(a1.x, 32);
    a1.y += __shfl_xor(a1.y, 16); a1.y += __shfl_xor(a1.y, 32);
    a1.z += __shfl_xor(a1.z, 16); a1.z += __shfl_xor(a1.z, 32);
    a1.w += __shfl_xor(a1.w, 16); a1.w += __shfl_xor(a1.w, 32);

    if (lane < 32) {                     // one coalesced 512 B store
        const uint2* xs2 = (const uint2*)xs4;
        int p = lane >> 4;               // float4 half: 0 or 1
        int f4 = (lane & 15) * 2 + p;    // float4 index 0..31
        float4 av = p ? a1 : a0;
        uint2 su = xs2[(size_t)n * 32 + f4];   // self-loop (4 bf16)
        acc4(av, su.x, su.y);
        float4 bb = ((const float4*)bias)[f4];
        float4 o;
        o.x = fmaxf(dv * av.x + bb.x, 0.f);
        o.y = fmaxf(dv * av.y + bb.y, 0.f);
        o.z = fmaxf(dv * av.z + bb.z, 0.f);
        o.w = fmaxf(dv * av.w + bb.w, 0.f);
        ((float4*)(out + (size_t)n * 128))[f4] = o;
    }
}

extern "C" void kernel_launch(void* const* d_in, const int* in_sizes, int n_in,
                              void* d_out, int out_size, void* d_ws, size_t ws_size,
                              hipStream_t stream) {
    const float* x   = (const float*)d_in[0];
    const int*   ei  = (const int*)d_in[1];     // [2, E] flat: src then dst
    const float* W   = (const float*)d_in[2];
    const float* b   = (const float*)d_in[3];
    float*       out = (float*)d_out;

    const int N = in_sizes[0] / 128;
    const int E = in_sizes[1] / 2;
    const int* src = ei;
    const int* dst = ei + E;

    const int B = (N + 127) >> 7;            // 782 buckets
    const int M = B * NP1;                   // scan entries
    const int chunk = (E + NP1 - 1) / NP1;   // edges per phase-1 block

    // workspace carve (256B aligned)
    auto align = [](size_t v) { return (v + 255) & ~(size_t)255; };
    char* p = (char*)d_ws;
    int*            hist     = (int*)p;            p += align((size_t)M * 4);
    int*            bsum     = (int*)p;            p += align(512 * 4);
    int*            rowptr   = (int*)p;            p += align(((size_t)N + 1) * 4);
    float*          dinv     = (float*)p;          p += align((size_t)N * 4);
    unsigned*       bucketed = (unsigned*)p;       p += align((size_t)E * 4);
    int*            csr_src  = (int*)p;            p += align((size_t)E * 4);
    unsigned*       xs       = (unsigned*)p;       p += align((size_t)N * 64 * 4);
    unsigned short* Wt       = (unsigned short*)p; p += align(128 * 128 * 2);
    (void)ws_size;

    const int nbM = (M + SCAN_BLK - 1) / SCAN_BLK;   // <=512 for scanB

    k_hist   <<<NP1, 256, 0, stream>>>(dst, hist, W, Wt, E, B, chunk);
    k_scanA  <<<nbM, 256, 0, stream>>>(hist, bsum, M);
    k_scanB  <<<1, 512, 0, stream>>>(bsum, nbM);
    k_scanC2 <<<nbM, 256, 0, stream>>>(hist, bsum, M);
    k_scatter<<<NP1, 256, 0, stream>>>(src, dst, hist, bucketed, E, B, chunk);
    k_csr    <<<B, 256, 0, stream>>>(bucketed, hist, csr_src, rowptr, dinv, E, B, N);
    k_gemm   <<<(N + 63) / 64, 256, 0, stream>>>(x, Wt, dinv, xs, N);
    k_aggregate<<<(N + 3) / 4, 256, 0, stream>>>((const uint4*)xs, csr_src, rowptr,
                                                 dinv, b, out, N);
}